// Round 9
// baseline (363.227 us; speedup 1.0000x reference)
//
#include <hip/hip_runtime.h>

#define K3   21504   // ATTR*C = 21*1024
#define C_   1024
#define NPIX 128     // H*W
#define NATTR 21
#define NB   4
#define ROWS 14      // W3 rows per wave
#define RPB  28      // rows per block (2 waves); 21504/28 = 768 blocks = 3/CU

typedef float f32x4 __attribute__((ext_vector_type(4)));

__device__ __forceinline__ float wave_reduce_sum(float v) {
  #pragma unroll
  for (int off = 32; off > 0; off >>= 1)
    v += __shfl_xor(v, off, 64);
  return v;
}

// ---- Kernel A: lq[b][o] = sum_k Q[b][k] * W3[o][k]  (the 1.85 GB stream) ----
// block = 128 (2 waves x ROWS=14 rows), 768 blocks = exactly 3/CU.
// Q phase (4 x 256 floats) staged in LDS, double-buffered, shared by both
// waves: Q L2 traffic 0.62 -> 0.26 GB vs R8. W3 rows stream through ping-pong
// VGPR buffers with NT loads. One barrier per 256-float phase.

#define FMA_TILE(W_)                                                   \
  {                                                                    \
    _Pragma("unroll")                                                  \
    for (int r = 0; r < ROWS; ++r)                                     \
      _Pragma("unroll")                                                \
      for (int b = 0; b < NB; ++b) {                                   \
        _Pragma("unroll")                                              \
        for (int e = 0; e < 4; ++e)                                    \
          acc[r][b] += W_[r][e] * q[b][e];                             \
      }                                                                \
  }

#define LOAD_W(W_, kk)                                                 \
  {                                                                    \
    _Pragma("unroll")                                                  \
    for (int r = 0; r < ROWS; ++r)                                     \
      W_[r] = __builtin_nontemporal_load(                              \
                 (const f32x4*)(r0 + (size_t)r * K3 + (kk)));          \
  }

#define LOAD_Q(bufi)                                                   \
  f32x4 q[NB];                                                         \
  {                                                                    \
    _Pragma("unroll")                                                  \
    for (int b = 0; b < NB; ++b)                                       \
      q[b] = *(const f32x4*)&qs[bufi][b][kl];                          \
  }

__global__ __launch_bounds__(128) void k_lq(
    const float* __restrict__ Q, const float* __restrict__ W3,
    float* __restrict__ lq) {
  const int t = threadIdx.x;
  const int wave = t >> 6, lane = t & 63;
  const int o0 = blockIdx.x * RPB + wave * ROWS;
  const float* r0 = W3 + (size_t)o0 * K3;
  __shared__ float qs[2][NB][256];
  const int sb = t >> 5;           // which batch row this thread stages
  const int so = (t & 31) * 8;     // 8 floats per thread per phase
  const float* qsrc = Q + (size_t)sb * K3 + so;
  const int kl = lane * 4;

  float acc[ROWS][NB];
  #pragma unroll
  for (int r = 0; r < ROWS; ++r)
    #pragma unroll
    for (int b = 0; b < NB; ++b) acc[r][b] = 0.f;

  f32x4 wA[ROWS], wB[ROWS];

  // prologue: stage phase 0 into buf0; load W phase 0 into wA
  {
    f32x4 s0 = *(const f32x4*)(qsrc);
    f32x4 s1 = *(const f32x4*)(qsrc + 4);
    *(f32x4*)&qs[0][sb][so]     = s0;
    *(f32x4*)&qs[0][sb][so + 4] = s1;
  }
  LOAD_W(wA, kl);
  __syncthreads();

  // 84 phases of 256 floats; 2 per iteration; phases 82,83 peeled.
  #pragma unroll 1
  for (int it = 0; it < 41; ++it) {
    const int p0 = 2 * it;
    {   // ---- phase p0 (buf0) ----
      f32x4 s0 = *(const f32x4*)(qsrc + (p0 + 1) * 256);
      f32x4 s1 = *(const f32x4*)(qsrc + (p0 + 1) * 256 + 4);
      LOAD_W(wB, (p0 + 1) * 256 + kl);
      LOAD_Q(0);
      FMA_TILE(wA);
      *(f32x4*)&qs[1][sb][so]     = s0;
      *(f32x4*)&qs[1][sb][so + 4] = s1;
      __syncthreads();
    }
    {   // ---- phase p0+1 (buf1) ----
      f32x4 s0 = *(const f32x4*)(qsrc + (p0 + 2) * 256);
      f32x4 s1 = *(const f32x4*)(qsrc + (p0 + 2) * 256 + 4);
      LOAD_W(wA, (p0 + 2) * 256 + kl);
      LOAD_Q(1);
      FMA_TILE(wB);
      *(f32x4*)&qs[0][sb][so]     = s0;
      *(f32x4*)&qs[0][sb][so + 4] = s1;
      __syncthreads();
    }
  }
  {   // ---- phase 82 (buf0) ----
    f32x4 s0 = *(const f32x4*)(qsrc + 83 * 256);
    f32x4 s1 = *(const f32x4*)(qsrc + 83 * 256 + 4);
    LOAD_W(wB, 83 * 256 + kl);
    LOAD_Q(0);
    FMA_TILE(wA);
    *(f32x4*)&qs[1][sb][so]     = s0;
    *(f32x4*)&qs[1][sb][so + 4] = s1;
    __syncthreads();
  }
  {   // ---- phase 83 (buf1) ----
    LOAD_Q(1);
    FMA_TILE(wB);
  }

  #pragma unroll
  for (int r = 0; r < ROWS; ++r)
    #pragma unroll
    for (int b = 0; b < NB; ++b) {
      float s = wave_reduce_sum(acc[r][b]);
      if (lane == 0) lq[(size_t)b * K3 + o0 + r] = s;
    }
}

// ---- Kernel C (fused): vu slices + d-dots ----
// blocks 0..1359   : vu[job][k] slices (85 jobs x 16 k-slices)
// blocks 1360..1444: d[job'] dots (job'<84: lq.b1 per (b,i); 84: fc_w.b2)
__global__ __launch_bounds__(256) void k_vu(
    const float* __restrict__ W1, const float* __restrict__ W2,
    const float* __restrict__ lq, const float* __restrict__ fc_w,
    const float* __restrict__ b1, const float* __restrict__ b2,
    float* __restrict__ vu, float* __restrict__ dc) {
  const int blk = blockIdx.x;
  if (blk >= 85 * 16) {
    const int xjob = blk - 85 * 16;
    if (threadIdx.x < 64) {
      const int lane = threadIdx.x;
      float acc = 0.f;
      if (xjob < NB * NATTR) {
        const int b = xjob / NATTR, i = xjob % NATTR;
        for (int c = lane; c < C_; c += 64)
          acc += lq[(size_t)b * K3 + c * NATTR + i] * b1[c];
      } else {
        for (int c = lane; c < C_; c += 64)
          acc += fc_w[c] * b2[c];
      }
      acc = wave_reduce_sum(acc);
      if (lane == 0) dc[xjob] = acc;
    }
    return;
  }
  const int job = blk >> 4;
  const int kc  = blk & 15;
  const int cg  = threadIdx.x >> 6;
  const int kl  = threadIdx.x & 63;
  const int k   = kc * 64 + kl;
  const float* M;
  const float* coef;
  int cstride;
  if (job < NB * NATTR) {
    M = W1;
    coef = lq + (size_t)(job / NATTR) * K3 + (job % NATTR);
    cstride = NATTR;
  } else {
    M = W2;
    coef = fc_w;
    cstride = 1;
  }
  float acc = 0.f;
  const int c0 = cg * 256;
  #pragma unroll 8
  for (int c = c0; c < c0 + 256; ++c)
    acc += coef[c * cstride] * M[(size_t)c * C_ + k];
  __shared__ float red[4][64];
  red[cg][kl] = acc;
  __syncthreads();
  if (threadIdx.x < 64) {
    float s = red[0][kl] + red[1][kl] + red[2][kl] + red[3][kl];
    vu[(size_t)job * C_ + k] = s;
  }
}

// ---- Kernel D: per (b,n): QK[i]=(v[b,i,:]·f[b,:,n]+d[b,i])/32, g=u·f+c0,
//      softmax over i, write P[b,i,n] = A[i]*g ----
__global__ __launch_bounds__(256) void k_attn(
    const float* __restrict__ f, const float* __restrict__ vu,
    const float* __restrict__ dc, float* __restrict__ P) {
  const int b = blockIdx.x >> 7;
  const int n = blockIdx.x & 127;
  const int t = threadIdx.x;
  const int wave = t >> 6, lane = t & 63;
  __shared__ float xs[C_];
  __shared__ float red[22][4];
  #pragma unroll
  for (int j = 0; j < 4; ++j) {
    int c = t + j * 256;
    xs[c] = f[((size_t)b * C_ + c) * NPIX + n];
  }
  __syncthreads();
  for (int ii = 0; ii < 22; ++ii) {
    const float* vec = vu + (size_t)((ii < NATTR) ? (b * NATTR + ii) : NB * NATTR) * C_;
    float p = 0.f;
    #pragma unroll
    for (int j = 0; j < 4; ++j) {
      int c = t + j * 256;
      p += xs[c] * vec[c];
    }
    p = wave_reduce_sum(p);
    if (lane == 0) red[ii][wave] = p;
  }
  __syncthreads();
  if (t == 0) {
    float qk[NATTR];
    float m = -1e30f;
    #pragma unroll
    for (int i = 0; i < NATTR; ++i) {
      qk[i] = (red[i][0] + red[i][1] + red[i][2] + red[i][3]
               + dc[b * NATTR + i]) * 0.03125f;   // 1/sqrt(1024)
      m = fmaxf(m, qk[i]);
    }
    float g = red[21][0] + red[21][1] + red[21][2] + red[21][3] + dc[NB * NATTR];
    float s = 0.f;
    #pragma unroll
    for (int i = 0; i < NATTR; ++i) { qk[i] = expf(qk[i] - m); s += qk[i]; }
    const float inv = g / s;
    #pragma unroll
    for (int i = 0; i < NATTR; ++i)
      P[(size_t)(b * NATTR + i) * NPIX + n] = qk[i] * inv;
  }
}

// ---- Kernel E: pred[b,i] = sum_n P[b,i,n] + fc_b ----
__global__ __launch_bounds__(64) void k_pred(
    const float* __restrict__ P, const float* __restrict__ fc_b,
    float* __restrict__ out) {
  const int job = blockIdx.x;
  const int lane = threadIdx.x;
  float acc = P[(size_t)job * NPIX + lane] + P[(size_t)job * NPIX + 64 + lane];
  acc = wave_reduce_sum(acc);
  if (lane == 0) out[job] = acc + fc_b[0];
}

extern "C" void kernel_launch(void* const* d_in, const int* in_sizes, int n_in,
                              void* d_out, int out_size, void* d_ws, size_t ws_size,
                              hipStream_t stream) {
  const float* feature = (const float*)d_in[0];
  const float* Q   = (const float*)d_in[1];
  const float* W1  = (const float*)d_in[2];
  const float* b1  = (const float*)d_in[3];
  const float* W2  = (const float*)d_in[4];
  const float* b2  = (const float*)d_in[5];
  const float* W3  = (const float*)d_in[6];
  const float* fcw = (const float*)d_in[7];
  const float* fcb = (const float*)d_in[8];
  float* out = (float*)d_out;

  float* ws = (float*)d_ws;
  float* lq = ws;                    // 4*21504      = 86016
  float* vu = lq + NB * K3;          // 85*1024      = 87040
  float* dc = vu + 85 * C_;          // 85
  float* P  = dc + 85;               // 84*128       = 10752

  hipLaunchKernelGGL(k_lq,   dim3(K3 / RPB), dim3(128), 0, stream, Q, W3, lq);
  hipLaunchKernelGGL(k_vu,   dim3(85 * 16 + 85), dim3(256), 0, stream,
                     W1, W2, lq, fcw, b1, b2, vu, dc);
  hipLaunchKernelGGL(k_attn, dim3(NB * NPIX), dim3(256), 0, stream, feature, vu, dc, P);
  hipLaunchKernelGGL(k_pred, dim3(NB * NATTR), dim3(64), 0, stream, P, fcb, out);
}

// Round 10
// 328.776 us; speedup vs baseline: 1.1048x; 1.1048x over previous
//
#include <hip/hip_runtime.h>

#define K3   21504   // ATTR*C = 21*1024
#define C_   1024
#define NPIX 128     // H*W
#define NATTR 21
#define NB   4
#define ROWS 12      // W3 rows per wave; 21504/12 = 1792 blocks = exactly 7/CU
                     // (ROWS=14 hits the 256-VGPR cliff; LDS-shared Q (R9) loses
                     // to barrier exposure. This is the measured optimum.)

typedef float f32x4 __attribute__((ext_vector_type(4)));

__device__ __forceinline__ float wave_reduce_sum(float v) {
  #pragma unroll
  for (int off = 32; off > 0; off >>= 1)
    v += __shfl_xor(v, off, 64);
  return v;
}

// ---- Kernel A: lq[b][o] = sum_k Q[b][k] * W3[o][k]  (the 1.85 GB stream) ----
// 1 wave per block, ROWS=12 rows per wave -> 1792 blocks = 7 per CU (balanced).
// Phase = 256 floats per row (one f32x4/lane); 84 phases; 2-phase pipeline.
// R8-verified: W3 read at 6.16 TB/s = 98% of m13 copy ceiling.

#define LOAD_TILE(W_, Q_, kk)                                          \
  {                                                                    \
    _Pragma("unroll")                                                  \
    for (int r = 0; r < ROWS; ++r)                                     \
      W_[r] = __builtin_nontemporal_load(                              \
                 (const f32x4*)(r0 + (size_t)r * K3 + (kk)));          \
    _Pragma("unroll")                                                  \
    for (int b = 0; b < NB; ++b)                                       \
      Q_[b] = *(const f32x4*)(Q + (size_t)b * K3 + (kk));              \
  }

#define FMA_TILE(W_, Q_)                                               \
  {                                                                    \
    _Pragma("unroll")                                                  \
    for (int r = 0; r < ROWS; ++r)                                     \
      _Pragma("unroll")                                                \
      for (int b = 0; b < NB; ++b) {                                   \
        _Pragma("unroll")                                              \
        for (int e = 0; e < 4; ++e)                                    \
          acc[r][b] += W_[r][e] * Q_[b][e];                            \
      }                                                                \
  }

__global__ __launch_bounds__(64) void k_lq(
    const float* __restrict__ Q, const float* __restrict__ W3,
    float* __restrict__ lq) {
  const int lane = threadIdx.x;
  const int o0 = blockIdx.x * ROWS;
  const float* r0 = W3 + (size_t)o0 * K3;
  float acc[ROWS][NB];
  #pragma unroll
  for (int r = 0; r < ROWS; ++r)
    #pragma unroll
    for (int b = 0; b < NB; ++b) acc[r][b] = 0.f;

  f32x4 wA[ROWS], qA[NB], wB[ROWS], qB[NB];
  int k = lane * 4;                 // element offset within a row
  LOAD_TILE(wA, qA, k);
  // 84 chunks of 256 floats; 2 per iteration; tail peeled.
  #pragma unroll 1
  for (int it = 0; it < 41; ++it) {
    LOAD_TILE(wB, qB, k + 256);
    FMA_TILE(wA, qA);
    LOAD_TILE(wA, qA, k + 512);
    FMA_TILE(wB, qB);
    k += 512;
  }
  LOAD_TILE(wB, qB, k + 256);
  FMA_TILE(wA, qA);
  FMA_TILE(wB, qB);

  #pragma unroll
  for (int r = 0; r < ROWS; ++r)
    #pragma unroll
    for (int b = 0; b < NB; ++b) {
      float s = wave_reduce_sum(acc[r][b]);
      if (lane == 0) lq[(size_t)b * K3 + o0 + r] = s;
    }
}

// ---- Kernel C (fused): vu slices + d-dots ----
// blocks 0..1359   : vu[job][k] slices (85 jobs x 16 k-slices)
// blocks 1360..1444: d[job'] dots (job'<84: lq.b1 per (b,i); 84: fc_w.b2)
__global__ __launch_bounds__(256) void k_vu(
    const float* __restrict__ W1, const float* __restrict__ W2,
    const float* __restrict__ lq, const float* __restrict__ fc_w,
    const float* __restrict__ b1, const float* __restrict__ b2,
    float* __restrict__ vu, float* __restrict__ dc) {
  const int blk = blockIdx.x;
  if (blk >= 85 * 16) {
    const int xjob = blk - 85 * 16;
    if (threadIdx.x < 64) {
      const int lane = threadIdx.x;
      float acc = 0.f;
      if (xjob < NB * NATTR) {
        const int b = xjob / NATTR, i = xjob % NATTR;
        for (int c = lane; c < C_; c += 64)
          acc += lq[(size_t)b * K3 + c * NATTR + i] * b1[c];
      } else {
        for (int c = lane; c < C_; c += 64)
          acc += fc_w[c] * b2[c];
      }
      acc = wave_reduce_sum(acc);
      if (lane == 0) dc[xjob] = acc;
    }
    return;
  }
  const int job = blk >> 4;
  const int kc  = blk & 15;
  const int cg  = threadIdx.x >> 6;
  const int kl  = threadIdx.x & 63;
  const int k   = kc * 64 + kl;
  const float* M;
  const float* coef;
  int cstride;
  if (job < NB * NATTR) {
    M = W1;
    coef = lq + (size_t)(job / NATTR) * K3 + (job % NATTR);
    cstride = NATTR;
  } else {
    M = W2;
    coef = fc_w;
    cstride = 1;
  }
  float acc = 0.f;
  const int c0 = cg * 256;
  #pragma unroll 8
  for (int c = c0; c < c0 + 256; ++c)
    acc += coef[c * cstride] * M[(size_t)c * C_ + k];
  __shared__ float red[4][64];
  red[cg][kl] = acc;
  __syncthreads();
  if (threadIdx.x < 64) {
    float s = red[0][kl] + red[1][kl] + red[2][kl] + red[3][kl];
    vu[(size_t)job * C_ + k] = s;
  }
}

// ---- Kernel D: per (b,n): QK[i]=(v[b,i,:]·f[b,:,n]+d[b,i])/32, g=u·f+c0,
//      softmax over i, write P[b,i,n] = A[i]*g ----
__global__ __launch_bounds__(256) void k_attn(
    const float* __restrict__ f, const float* __restrict__ vu,
    const float* __restrict__ dc, float* __restrict__ P) {
  const int b = blockIdx.x >> 7;
  const int n = blockIdx.x & 127;
  const int t = threadIdx.x;
  const int wave = t >> 6, lane = t & 63;
  __shared__ float xs[C_];
  __shared__ float red[22][4];
  #pragma unroll
  for (int j = 0; j < 4; ++j) {
    int c = t + j * 256;
    xs[c] = f[((size_t)b * C_ + c) * NPIX + n];
  }
  __syncthreads();
  for (int ii = 0; ii < 22; ++ii) {
    const float* vec = vu + (size_t)((ii < NATTR) ? (b * NATTR + ii) : NB * NATTR) * C_;
    float p = 0.f;
    #pragma unroll
    for (int j = 0; j < 4; ++j) {
      int c = t + j * 256;
      p += xs[c] * vec[c];
    }
    p = wave_reduce_sum(p);
    if (lane == 0) red[ii][wave] = p;
  }
  __syncthreads();
  if (t == 0) {
    float qk[NATTR];
    float m = -1e30f;
    #pragma unroll
    for (int i = 0; i < NATTR; ++i) {
      qk[i] = (red[i][0] + red[i][1] + red[i][2] + red[i][3]
               + dc[b * NATTR + i]) * 0.03125f;   // 1/sqrt(1024)
      m = fmaxf(m, qk[i]);
    }
    float g = red[21][0] + red[21][1] + red[21][2] + red[21][3] + dc[NB * NATTR];
    float s = 0.f;
    #pragma unroll
    for (int i = 0; i < NATTR; ++i) { qk[i] = expf(qk[i] - m); s += qk[i]; }
    const float inv = g / s;
    #pragma unroll
    for (int i = 0; i < NATTR; ++i)
      P[(size_t)(b * NATTR + i) * NPIX + n] = qk[i] * inv;
  }
}

// ---- Kernel E: pred[b,i] = sum_n P[b,i,n] + fc_b ----
__global__ __launch_bounds__(64) void k_pred(
    const float* __restrict__ P, const float* __restrict__ fc_b,
    float* __restrict__ out) {
  const int job = blockIdx.x;
  const int lane = threadIdx.x;
  float acc = P[(size_t)job * NPIX + lane] + P[(size_t)job * NPIX + 64 + lane];
  acc = wave_reduce_sum(acc);
  if (lane == 0) out[job] = acc + fc_b[0];
}

extern "C" void kernel_launch(void* const* d_in, const int* in_sizes, int n_in,
                              void* d_out, int out_size, void* d_ws, size_t ws_size,
                              hipStream_t stream) {
  const float* feature = (const float*)d_in[0];
  const float* Q   = (const float*)d_in[1];
  const float* W1  = (const float*)d_in[2];
  const float* b1  = (const float*)d_in[3];
  const float* W2  = (const float*)d_in[4];
  const float* b2  = (const float*)d_in[5];
  const float* W3  = (const float*)d_in[6];
  const float* fcw = (const float*)d_in[7];
  const float* fcb = (const float*)d_in[8];
  float* out = (float*)d_out;

  float* ws = (float*)d_ws;
  float* lq = ws;                    // 4*21504      = 86016
  float* vu = lq + NB * K3;          // 85*1024      = 87040
  float* dc = vu + 85 * C_;          // 85
  float* P  = dc + 85;               // 84*128       = 10752

  hipLaunchKernelGGL(k_lq,   dim3(K3 / ROWS), dim3(64), 0, stream, Q, W3, lq);
  hipLaunchKernelGGL(k_vu,   dim3(85 * 16 + 85), dim3(256), 0, stream,
                     W1, W2, lq, fcw, b1, b2, vu, dc);
  hipLaunchKernelGGL(k_attn, dim3(NB * NPIX), dim3(256), 0, stream, feature, vu, dc, P);
  hipLaunchKernelGGL(k_pred, dim3(NB * NATTR), dim3(64), 0, stream, P, fcb, out);
}